// Round 13
// baseline (146.201 us; speedup 1.0000x reference)
//
#include <hip/hip_runtime.h>
#include <hip/hip_bf16.h>
#include <stdint.h>

// MoE: B=8, N=8192, D=128, C=128, E=8, K=2. Tokens T = 65536.
#define Dd 128
#define Cc 128
#define Ee 8
#define TM 128          // tokens per block (8 waves x 32x64 sub-tiles)
#define NTHR 512
#define NTOK 65536
#define GSTR 9          // glg row stride (pad: kills 4-way bank conflict)

using f32x4  = __attribute__((ext_vector_type(4))) float;
using short8 = __attribute__((ext_vector_type(8))) short;
typedef unsigned short u16;

__device__ inline u16 f2bf(float f) {
    union { __hip_bfloat16 h; u16 u; } cv;
    cv.h = __float2bfloat16(f);
    return cv.u;
}

// expert_w [E][D][C] fp32 -> wt = swizzled W^T bf16 (chunk (c,cc) at slot
// cc^(c&7) so a LINEAR LDS copy yields the swizzled tile).
// Coalesced LDS-transpose version: block = (e, dblk of 16 d-rows).
__global__ __launch_bounds__(256) void transpose_w(const float* __restrict__ w,
                                                   u16* __restrict__ wt) {
    __shared__ u16 T[16][132];                 // padded stride
    int e    = blockIdx.x >> 3;
    int dblk = blockIdx.x & 7;
    int tid  = threadIdx.x;
    {
        int dl = tid >> 7;                     // 2 d-rows per iter
        int c  = tid & 127;
        const float* src = w + (e << 14) + ((dblk * 16) << 7) + c;
        #pragma unroll
        for (int i = 0; i < 8; ++i) {
            int d = i * 2 + dl;
            T[d][c] = f2bf(src[d << 7]);       // coalesced fp32 reads
        }
    }
    __syncthreads();
    {
        int c2 = tid >> 1, j = tid & 1;
        int cc = dblk * 2 + j;                 // global 8-d chunk index
        u16 tmp[8];
        #pragma unroll
        for (int k = 0; k < 8; ++k) tmp[k] = T[j * 8 + k][c2];
        int slot = cc ^ (c2 & 7);
        *(int4*)&wt[(e << 14) + (c2 << 7) + (slot << 3)] = *(const int4*)tmp;
    }
}

__global__ __launch_bounds__(NTHR, 4) void moe_main(
    const float* __restrict__ x,    // [T][D]
    const float* __restrict__ rw,   // [D][E]
    const float* __restrict__ rb,   // [E]
    const float* __restrict__ eb,   // [E][C]
    const u16*   __restrict__ wt,   // [E] swizzled W^T bf16
    float*       __restrict__ out)  // [T][C]
{
    __shared__ __align__(16) u16 Ws[2][Cc * Dd];   // 2 x 32 KB double buffer
    __shared__ float glg[TM * GSTR];               // logits, then gates

    const int tid  = threadIdx.x;
    const int t0   = blockIdx.x * TM;
    const int lane = tid & 63;
    const int wave = tid >> 6;           // 0..7
    const int m0   = (wave >> 1) * 32;   // wave -> 32x64 output sub-tile
    const int n0   = (wave & 1) * 64;
    const int ln15 = lane & 15;
    const int kg   = lane >> 4;

    // ---- issue W[0] loads first (deepest latency) ----
    int4 rstg[4];
    {
        const int4* src = (const int4*)wt;         // expert 0
        #pragma unroll
        for (int j = 0; j < 4; ++j) rstg[j] = src[j * NTHR + tid];
    }

    // ---- router logits from GLOBAL x; fp64 acc (exact expert selection) ----
    {
        int p  = tid * 2;                 // 1024 (token,expert) slots
        int tk = p >> 3, e0 = p & 7;
        const float4* xr = (const float4*)(x + (size_t)(t0 + tk) * Dd);
        double a0 = (double)rb[e0], a1 = (double)rb[e0 + 1];
        #pragma unroll 8
        for (int q = 0; q < 32; ++q) {
            float4 v = xr[q];
            #pragma unroll
            for (int u = 0; u < 4; ++u) {
                double xv = (double)((const float*)&v)[u];
                a0 += xv * (double)rw[(q * 4 + u) * Ee + e0];
                a1 += xv * (double)rw[(q * 4 + u) * Ee + e0 + 1];
            }
        }
        glg[tk * GSTR + e0]     = (float)a0;
        glg[tk * GSTR + e0 + 1] = (float)a1;
    }

    // ---- A-fragments direct from global x (L1/L2-hot), expert-invariant ----
    short8 af[2][4];
    #pragma unroll
    for (int mi = 0; mi < 2; ++mi) {
        int r = t0 + m0 + mi * 16 + ln15;
        #pragma unroll
        for (int ks = 0; ks < 4; ++ks) {
            const float4* s = (const float4*)(x + (size_t)r * Dd + (ks * 4 + kg) * 8);
            float4 a = s[0], b = s[1];
            short8 v;
            v[0] = (short)f2bf(a.x); v[1] = (short)f2bf(a.y);
            v[2] = (short)f2bf(a.z); v[3] = (short)f2bf(a.w);
            v[4] = (short)f2bf(b.x); v[5] = (short)f2bf(b.y);
            v[6] = (short)f2bf(b.z); v[7] = (short)f2bf(b.w);
            af[mi][ks] = v;
        }
    }

    // ---- write staged W[0] to LDS ----
    {
        int4* dst = (int4*)Ws[0];
        #pragma unroll
        for (int j = 0; j < 4; ++j) dst[j * NTHR + tid] = rstg[j];
    }
    __syncthreads();   // Ws[0] + logits visible

    // ---- gates (tid<TM); consumed after iter-0 barrier ----
    if (tid < TM) {
        float l[Ee];
        #pragma unroll
        for (int k = 0; k < Ee; ++k) l[k] = glg[tid * GSTR + k];
        int e0 = 0;
        #pragma unroll
        for (int k = 1; k < Ee; ++k) if (l[k] > l[e0]) e0 = k;
        int e1 = (e0 == 0) ? 1 : 0;
        #pragma unroll
        for (int k = 0; k < Ee; ++k)
            if (k != e0 && l[k] > l[e1]) e1 = k;
        float g1 = __expf(l[e1] - l[e0]);
        float s  = 1.0f + g1;
        float g0 = 1.0f / s; g1 = g1 / s;
        #pragma unroll
        for (int k = 0; k < Ee; ++k) glg[tid * GSTR + k] = 0.0f;
        glg[tid * GSTR + e0] = g0;
        glg[tid * GSTR + e1] = g1;
    }

    f32x4 oacc[2][4] = {};

    for (int e = 0; e < Ee; ++e) {
        // issue next expert's loads (fly under this expert's MFMA)
        if (e < Ee - 1) {
            const int4* src = (const int4*)(wt + ((size_t)(e + 1) << 14));
            #pragma unroll
            for (int j = 0; j < 4; ++j) rstg[j] = src[j * NTHR + tid];
        }

        const u16* wsc = Ws[e & 1];
        f32x4 acc[2][4] = {};
        #pragma unroll
        for (int ks = 0; ks < 4; ++ks) {
            short8 bfr[4];
            int cc = ks * 4 + kg;
            #pragma unroll
            for (int ni = 0; ni < 4; ++ni) {
                int r = n0 + ni * 16 + ln15;
                bfr[ni] = *(const short8*)&wsc[r * Dd + ((cc ^ (r & 7)) << 3)];
            }
            #pragma unroll
            for (int mi = 0; mi < 2; ++mi)
                #pragma unroll
                for (int ni = 0; ni < 4; ++ni)
                    acc[mi][ni] = __builtin_amdgcn_mfma_f32_16x16x32_bf16(
                        af[mi][ks], bfr[ni], acc[mi][ni], 0, 0, 0);
        }

        // write next buffer (prev reads of it fenced by last barrier)
        if (e < Ee - 1) {
            int4* dst = (int4*)Ws[(e + 1) & 1];
            #pragma unroll
            for (int j = 0; j < 4; ++j) dst[j * NTHR + tid] = rstg[j];
        }
        __syncthreads();   // next Ws ready; (e==0) gates now visible

        // gated accumulate: oacc += g * (acc + bias)
        float bb[4];
        #pragma unroll
        for (int ni = 0; ni < 4; ++ni) bb[ni] = eb[e * Cc + n0 + ni * 16 + ln15];
        #pragma unroll
        for (int mi = 0; mi < 2; ++mi)
            #pragma unroll
            for (int r = 0; r < 4; ++r) {
                float g = glg[(m0 + mi * 16 + kg * 4 + r) * GSTR + e];
                #pragma unroll
                for (int ni = 0; ni < 4; ++ni)
                    oacc[mi][ni][r] += g * (acc[mi][ni][r] + bb[ni]);
            }
    }

    // ---- write out ----
    #pragma unroll
    for (int mi = 0; mi < 2; ++mi)
        #pragma unroll
        for (int r = 0; r < 4; ++r) {
            size_t row = (size_t)(t0 + m0 + mi * 16 + kg * 4 + r);
            #pragma unroll
            for (int ni = 0; ni < 4; ++ni)
                out[row * Cc + n0 + ni * 16 + ln15] = oacc[mi][ni][r];
        }
}

extern "C" void kernel_launch(void* const* d_in, const int* in_sizes, int n_in,
                              void* d_out, int out_size, void* d_ws, size_t ws_size,
                              hipStream_t stream) {
    const float* x  = (const float*)d_in[0];
    const float* rw = (const float*)d_in[1];
    const float* rb = (const float*)d_in[2];
    const float* ew = (const float*)d_in[3];
    const float* eb = (const float*)d_in[4];
    float* out = (float*)d_out;
    u16* wt = (u16*)d_ws;                       // 256 KB swizzled bf16 W^T

    transpose_w<<<dim3(64), dim3(256), 0, stream>>>(ew, wt);
    moe_main<<<dim3(NTOK / TM), dim3(NTHR), 0, stream>>>(x, rw, rb, eb, wt, out);
}